// Round 5
// baseline (5041.388 us; speedup 1.0000x reference)
//
#include <hip/hip_runtime.h>
#include <cstddef>
#include <cstdint>

// CubicRNN MI355X — round 9: r8 + latency hoisting. All phase-2/3/4 global
// READS (cz/cx state, wy, biases, w_last) are staged into LDS during phase 0,
// overlapped with the halo load and hidden under the K-loop; gating runs on
// all 512 threads (r-pairs split across thread halves, exch reads broadcast).
// Grid, buffer geometry, and every global address stream unchanged from r8
// (r5/r6 proved re-based buffer geometry triggers 13-19x write amplification).
// wy staged with stride 65 (stride-64 LDS layout = 32-way bank conflict).
// Numerics bit-identical to r4..r8 (absmax 3.72529e-09).
// B=4, T=10, C=1, H=W=64, HC=32, S=3, L=3, kx=3, kz=5, ky=1, 18 steps.

typedef __attribute__((ext_vector_type(8))) _Float16 f16x8;
typedef __attribute__((ext_vector_type(4))) float f32x4;
typedef unsigned short u16;

#define HW 4096
#define NB 4

__device__ __forceinline__ float sigm(float x){ return 1.f/(1.f+expf(-x)); }
__device__ __forceinline__ u16 f2h(float x){
  _Float16 h = (_Float16)x;
  union { _Float16 f; u16 u; } c; c.f = h; return c.u;
}

__global__ __launch_bounds__(256) void zero4(uint4* __restrict__ p, size_t n){
  size_t i = (size_t)blockIdx.x*blockDim.x + threadIdx.x;
  size_t st = (size_t)gridDim.x*blockDim.x;
  uint4 z = make_uint4(0u,0u,0u,0u);
  for (; i < n; i += st) p[i] = z;
}

// Pack conv weights (fp32 OIHW) -> [unit=tap*3+kc][co(128)][k(32)] f16 single,
// cat channels remapped to uniform 96 (layer0: ci0->k0, ci1..64->k32..95).
__global__ __launch_bounds__(256) void pack_w(const float* __restrict__ src,
    u16* __restrict__ dst, int taps, int cin, int l0){
  int idx = blockIdx.x*256 + threadIdx.x;
  int k = idx & 31, co = (idx>>5) & 127, rest = idx >> 12;
  int tap = rest/3, kc = rest - tap*3;
  int p = kc*32 + k;
  int ci = l0 ? ((p==0) ? 0 : ((p>=32) ? p-31 : -1)) : p;
  float wv = 0.f;
  if (ci >= 0 && ci < cin) wv = src[((size_t)co*cin + ci)*taps + tap];
  dst[idx] = f2h(wv);
}

// cat layout: [b][chunk 0..23][pixel 0..4095][elem 0..7] f16; only chunks
// 0..11 (hi) are live. chunk = slot>>3, elem = slot&7 (slot 0..95).
// Chunks 12..23 are dead padding (address-geometry pinned to r4).
__device__ __forceinline__ void put_hi(u16* base, int b, int slot, int pix, float v){
  size_t o = ((size_t)(b*24 + (slot>>3))*4096 + pix)*8 + (slot&7);
  base[o] = f2h(v);
}

// Write frame (or fed-back pred) into slot 0 of layer-0 cat bufs.
__global__ __launch_bounds__(256) void frame_fill(const float* __restrict__ inseq,
    const float* __restrict__ predbuf, int step,
    u16* __restrict__ c0, u16* __restrict__ c1, u16* __restrict__ c2){
  int s = blockIdx.y;
  u16* dst = (s==0) ? c0 : ((s==1) ? c1 : c2);
  int i = blockIdx.x*256 + threadIdx.x;          // b*4096 + px
  int b = i >> 12, px = i & 4095;
  int j = step + s;
  float v = (j < 10) ? inseq[((size_t)b*10 + j)*HW + px]
                     : predbuf[(size_t)(j-3)*(NB*HW) + (size_t)b*HW + px];
  put_hi(dst, b, 0, px, v);
}

struct CellArgs {
  const u16* cat_in;                       // chunk-planar f16 (12 live chunks)
  const u16* wz; const u16* wx;            // packed f16 weights
  const float *bx, *bz;                    // [128]
  const float* cx_src; float* cx_dst;      // [B][4096][32] fp32 (dst may be null)
  float* cz;                               // in-place
  u16 *hx0, *hx1, *hz, *y_dst;             // cat base pointers (null = skip)
  const float *wy, *by;                    // [32][64],[32]
  const float *wl;                         // [32]; non-null = pred mode
  float *pred_out;                         // predbuf slot [B][4096]
  float *final_out;                        // d_out + ti*4096 (b-stride 40960) or null
};

// LDS map (byte offsets):
//   exch  f32x4 [0, 65536)      — halo (12 planes x 145 uint4 = 27,840 B)
//                                  overlays [0,27840) during phases 0-1
//   czL   f32   [65536, 73728)  — staged cz state  [64px][32ch]
//   cxL   f32   [73728, 81920)  — staged cx state  [64px][32ch]
//   wyl   f32   [81920, 90240)  — staged wy, stride 65 (bank-conflict-free)
//   bzL   f32   [90240, 90752)  — staged bz [128]
//   bxL   f32   [90752, 91264)  — staged bx [128]
//   byL   f32   [91264, 91392)  — staged by [32]
//   wlL   f32   [91392, 91520)  — staged w_last [32]
//   hbufF f32   [91520, 108928) — [64px][68]
//   ybufF f32   [108928, 118400)— [64px][37]
#define LDS_BYTES 118400

__global__ __launch_bounds__(512, 2) void cell_kernel(CellArgs a){
  __shared__ __align__(16) char smem[LDS_BYTES];
  uint4* AU4   = (uint4*)smem;
  f32x4* exch  = (f32x4*)smem;             // 4096 entries = 64 KB
  float* czL   = (float*)(smem + 65536);
  float* cxL   = (float*)(smem + 73728);
  float* wyl   = (float*)(smem + 81920);
  float* bzL   = (float*)(smem + 90240);
  float* bxL   = (float*)(smem + 90752);
  float* byL   = (float*)(smem + 91264);
  float* wlL   = (float*)(smem + 91392);
  float* hbufF = (float*)(smem + 91520);
  float* ybufF = (float*)(smem + 108928);

  const int tid = threadIdx.x;
  const int b = blockIdx.y;
  const int reg = blockIdx.x;
  const int R0 = (reg >> 3) << 3, C0 = (reg & 7) << 3;   // 8x8 pixel region

  // ---- phase 0: stage halo + state + epilogue weights (all overlapped) ----
  for (int i = tid; i < 1728; i += 512) {
    int px = i % 144, cp = i / 144;
    int hr = px / 12, hc = px - hr*12;
    int gy = R0 + hr - 2, gx = C0 + hc - 2;
    uint4 v = make_uint4(0u,0u,0u,0u);
    if (gy >= 0 && gy < 64 && gx >= 0 && gx < 64)
      v = *reinterpret_cast<const uint4*>(a.cat_in + ((size_t)(b*24 + cp)*4096 + gy*64 + gx)*8);
    AU4[cp*145 + px] = v;
  }
  // cell state for this region: [64px][32ch] fp32 each, coalesced 128B/px
  for (int i = tid; i < 2048; i += 512) {
    int px = i >> 5, ch = i & 31;
    int pxg = (R0 + (px >> 3))*64 + C0 + (px & 7);
    size_t gi = ((size_t)b*4096 + pxg)*32 + ch;
    czL[i] = a.cz[gi];
    cxL[i] = a.cx_src[gi];
  }
  if (a.wy) {
    for (int i = tid; i < 2048; i += 512)
      wyl[(i >> 6)*65 + (i & 63)] = a.wy[i];     // stride 65: conflict-free
    if (tid < 32) byL[tid] = a.by[tid];
  }
  if (tid < 128) { bzL[tid] = a.bz[tid]; bxL[tid] = a.bx[tid]; }
  if (a.wl && tid < 32) wlL[tid] = a.wl[tid];
  __syncthreads();

  // ---- phase 1: K-loop, Ng=2 (64 co/wave) x Kg=4; hi-half MFMAs only ----
  const int wave = tid >> 6, lane = tid & 63;
  const int n = wave & 1, kg = wave >> 1;
  const int q = lane >> 4, n16 = lane & 15;
  const int row_in = n16 >> 3, col = n16 & 7;
  const int cb = n*64;
  const int wlo = (cb + n16)*32 + q*8;     // lane weight offset (nf adds 512)

  f32x4 zf = {0.f,0.f,0.f,0.f};
  f32x4 accz[4][4], accx[4][4];            // [nf][m]
#pragma unroll
  for (int nf = 0; nf < 4; ++nf)
#pragma unroll
    for (int m = 0; m < 4; ++m) { accz[nf][m] = zf; accx[nf][m] = zf; }

  f16x8 Bz[4];
#pragma unroll
  for (int nf = 0; nf < 4; ++nf)
    Bz[nf] = *(const f16x8*)(a.wz + (size_t)kg*4096 + wlo + nf*512);

#pragma unroll 1
  for (int u = kg; u < 75; u += 4) {
    int tap = u/3, kc = u - tap*3;
    int ky = tap/5, kx = tap - ky*5;
    bool inner = ((unsigned)(ky-1) <= 2u) && ((unsigned)(kx-1) <= 2u);

    f16x8 Bx[4];
    if (inner) {
      int xu = ((ky-1)*3 + (kx-1))*3 + kc;
#pragma unroll
      for (int nf = 0; nf < 4; ++nf)
        Bx[nf] = *(const f16x8*)(a.wx + (size_t)xu*4096 + wlo + nf*512);
    }

    int ai0 = (kc*4 + q)*145 + (row_in + ky)*12 + col + kx;
    f16x8 Ah[4];
#pragma unroll
    for (int m = 0; m < 4; ++m)
      Ah[m] = *(const f16x8*)(AU4 + ai0 + m*24);

#pragma unroll
    for (int nf = 0; nf < 4; ++nf)
#pragma unroll
      for (int m = 0; m < 4; ++m)
        accz[nf][m] = __builtin_amdgcn_mfma_f32_16x16x32_f16(Ah[m], Bz[nf], accz[nf][m], 0,0,0);

    // prefetch next z-B (depth-1, hides L2 latency)
    int un = (u + 4 < 75) ? u + 4 : kg;
    f16x8 Bzn[4];
#pragma unroll
    for (int nf = 0; nf < 4; ++nf)
      Bzn[nf] = *(const f16x8*)(a.wz + (size_t)un*4096 + wlo + nf*512);

    if (inner) {
#pragma unroll
      for (int nf = 0; nf < 4; ++nf)
#pragma unroll
        for (int m = 0; m < 4; ++m)
          accx[nf][m] = __builtin_amdgcn_mfma_f32_16x16x32_f16(Ah[m], Bx[nf], accx[nf][m], 0,0,0);
    }
#pragma unroll
    for (int nf = 0; nf < 4; ++nf) Bz[nf] = Bzn[nf];
  }

  // ---- phase 2: K-reduce (4-way) fused with gating, 4 passes, 512 thr ----
  for (int pass = 0; pass < 4; ++pass) {
    const int br = pass >> 1, mh = pass & 1;       // br0=z, br1=x; Mfrags {2mh,2mh+1}
    __syncthreads();                               // exch free (halo dead / prev pass read)
#pragma unroll
    for (int nf = 0; nf < 4; ++nf)
#pragma unroll
      for (int ml = 0; ml < 2; ++ml) {
        int m = mh*2 + ml;
        exch[((((kg*2 + n)*4 + nf)*2 + ml)*64) + lane] = br ? accx[nf][m] : accz[nf][m];
      }
    __syncthreads();
    {
      int tg = tid >> 8;                           // r-pair selector (0..1)
      int t2 = tid & 255;
      int ch = t2 & 31, pxq = t2 >> 5;             // 8 px-quads x 32 channels
      int ml = pxq >> 2, qq = pxq & 3;
      const float* bias = br ? bxL : bzL;
      float gsum[4][4];                            // [gate][r]
#pragma unroll
      for (int g = 0; g < 4; ++g) {
        int co = g*32 + ch;
        int nn = co >> 6, nf = (co >> 4) & 3, nl = co & 15;
        int li = qq*16 + nl;
        f32x4 s = zf;
#pragma unroll
        for (int kgg = 0; kgg < 4; ++kgg)
          s += exch[((((kgg*2 + nn)*4 + nf)*2 + ml)*64) + li];
        float bb = bias[co];
#pragma unroll
        for (int r = 0; r < 4; ++r) gsum[g][r] = s[r] + bb;
      }
#pragma unroll
      for (int rr = 0; rr < 2; ++rr) {
        int r = tg*2 + rr;
        int p16 = qq*4 + r;
        int m = mh*2 + ml;
        int px = (2*m + (p16 >> 3))*8 + (p16 & 7);
        int pxg = (R0 + (px >> 3))*64 + C0 + (px & 7);
        size_t pix = (size_t)b*4096 + pxg;
        float ig = gsum[0][r], fg = gsum[1][r], gg = gsum[2][r], og = gsum[3][r];
        if (br == 0) {                             // z-branch
          float c = czL[px*32 + ch];
          float cn = sigm(fg + 0.01f)*c + sigm(ig)*tanhf(gg);
          float h = sigm(og)*tanhf(cn);
          a.cz[pix*32 + ch] = cn;
          if (a.hz) put_hi(a.hz, b, 64 + ch, pxg, h);
          hbufF[px*68 + 32 + ch] = h;
        } else {                                   // x-branch
          float c = cxL[px*32 + ch];
          float cn = sigm(fg + 0.01f)*c + sigm(ig)*tanhf(gg);
          float h = sigm(og)*tanhf(cn);
          if (a.cx_dst) a.cx_dst[pix*32 + ch] = cn;
          if (a.hx0) put_hi(a.hx0, b, 32 + ch, pxg, h);
          if (a.hx1) put_hi(a.hx1, b, 32 + ch, pxg, h);
          hbufF[px*68 + ch] = h;
        }
      }
    }
  }
  __syncthreads();

  // ---- phase 3: fused 1x1 y-conv (64 -> 32), weights from LDS ----
  if (a.wy) {
#pragma unroll 1
    for (int it = 0; it < 4; ++it) {
      int idx = tid + it*512;
      int co2 = idx & 31, px = idx >> 5;
      int pxg = (R0 + (px >> 3))*64 + C0 + (px & 7);
      float acc = byL[co2];
#pragma unroll
      for (int c2 = 0; c2 < 64; ++c2) acc += wyl[co2*65 + c2] * hbufF[px*68 + c2];
      if (a.y_dst) put_hi(a.y_dst, b, co2, pxg, acc);
      if (a.wl) ybufF[px*37 + co2] = acc;
    }
  }
  // ---- phase 4: fused pred-conv (32 -> 1), last cell only ----
  if (a.wl) {
    __syncthreads();
    if (tid < 64) {
      int px = tid;
      int pxg = (R0 + (px >> 3))*64 + C0 + (px & 7);
      float p = 0.f;
#pragma unroll
      for (int c2 = 0; c2 < 32; ++c2) p += wlL[c2] * ybufF[px*37 + c2];
      a.pred_out[(size_t)b*4096 + pxg] = p;
      if (a.final_out) a.final_out[(size_t)b*40960 + pxg] = p;
    }
  }
}

extern "C" void kernel_launch(void* const* d_in, const int* in_sizes, int n_in,
                              void* d_out, int out_size, void* d_ws, size_t ws_size,
                              hipStream_t stream)
{
  const float* input_seq = (const float*)d_in[0];
  const float* w_x0 = (const float*)d_in[1];
  const float* b_x0 = (const float*)d_in[2];
  const float* w_z0 = (const float*)d_in[3];
  const float* b_z0 = (const float*)d_in[4];
  const float* w_y0 = (const float*)d_in[5];
  const float* b_y0 = (const float*)d_in[6];
  const float* w_x1 = (const float*)d_in[7];
  const float* b_x1 = (const float*)d_in[8];
  const float* w_z1 = (const float*)d_in[9];
  const float* b_z1 = (const float*)d_in[10];
  const float* w_y1 = (const float*)d_in[11];
  const float* b_y1 = (const float*)d_in[12];
  const float* w_last = (const float*)d_in[13];
  (void)in_sizes; (void)n_in; (void)out_size; (void)ws_size;

  uint8_t* wsb = (uint8_t*)d_ws;
  size_t off = 0;
  auto alloc = [&](size_t bytes) -> void* {
    void* p = wsb + off; off += (bytes + 255) & ~(size_t)255; return p;
  };

  const size_t CATB = (size_t)NB*24*4096*8*2;    // 6,291,456 B (geometry pinned; lo half dead)
  u16* cat[3][3][2];
  for (int l = 0; l < 3; ++l)
    for (int s = 0; s < 3; ++s) {
      cat[l][s][0] = (u16*)alloc(CATB);
      cat[l][s][1] = (s == 0) ? (u16*)alloc(CATB) : cat[l][s][0];
    }
  const size_t CB = (size_t)NB*HW*32*4;          // 2,097,152 B
  float* cx[3][2]; float* cz[3];
  for (int l = 0; l < 3; ++l) { cx[l][0] = (float*)alloc(CB); cx[l][1] = (float*)alloc(CB); }
  for (int l = 0; l < 3; ++l) cz[l] = (float*)alloc(CB);
  size_t zero_bytes = off;                       // cats + cx + cz

  u16 *wzb[9], *wxb[9];
  for (int c = 0; c < 9; ++c) {
    wzb[c] = (u16*)alloc(75*4096*2);             // 25 taps x 3 kc x 128 co x 32 k
    wxb[c] = (u16*)alloc(27*4096*2);             // 9 taps x 3 kc
  }
  float* predbuf = (float*)alloc((size_t)18*NB*HW*4);

  zero4<<<2048, 256, 0, stream>>>((uint4*)wsb, zero_bytes/16);

  for (int l = 0; l < 3; ++l)
    for (int s = 0; s < 3; ++s) {
      int cell = l*3 + s;
      const float *srcx, *srcz; int cin;
      if (l == 0) { srcx = w_x0 + (size_t)s*128*65*9;  srcz = w_z0 + (size_t)s*128*65*25;  cin = 65; }
      else { int li = (l-1)*3 + s;
             srcx = w_x1 + (size_t)li*128*96*9; srcz = w_z1 + (size_t)li*128*96*25; cin = 96; }
      pack_w<<<(75*4096)/256, 256, 0, stream>>>(srcz, wzb[cell], 25, cin, l==0);
      pack_w<<<(27*4096)/256, 256, 0, stream>>>(srcx, wxb[cell], 9, cin, l==0);
    }

  for (int step = 0; step < 18; ++step) {
    int par = step & 1, npar = par ^ 1;
    frame_fill<<<dim3(64,3), 256, 0, stream>>>(input_seq, predbuf, step,
        cat[0][0][par], cat[0][1][0], cat[0][2][0]);
    for (int l = 0; l < 3; ++l)
      for (int s = 0; s < 3; ++s) {
        int cell = l*3 + s;
        CellArgs A;
        A.cat_in = cat[l][s][(s==0) ? par : 0];
        A.wz = wzb[cell]; A.wx = wxb[cell];
        if (l == 0) { A.bx = b_x0 + s*128; A.bz = b_z0 + s*128; }
        else { int li = (l-1)*3 + s; A.bx = b_x1 + li*128; A.bz = b_z1 + li*128; }
        A.cx_src = (s == 2) ? cx[l][1] : cx[l][0];
        A.cx_dst = (s == 0) ? cx[l][0] : ((s == 1) ? cx[l][1] : nullptr);
        A.cz = cz[l];
        A.hx0 = (s == 0) ? cat[l][1][0] : ((s == 1) ? cat[l][2][0] : nullptr);
        A.hx1 = (s == 0) ? cat[l][0][npar] : nullptr;
        A.hz  = (s < 2) ? cat[l][s+1][0] : cat[l][0][npar];
        A.wy = nullptr; A.by = nullptr; A.y_dst = nullptr;
        A.wl = nullptr; A.pred_out = nullptr; A.final_out = nullptr;
        if (l < 2) {
          if (l == 0) { A.wy = w_y0 + (size_t)s*32*64; A.by = b_y0 + s*32; }
          else        { A.wy = w_y1 + (size_t)s*32*64; A.by = b_y1 + s*32; }
          A.y_dst = cat[l+1][s][(s==0) ? par : 0];
        } else if (s == 2) {
          A.wy = w_y1 + (size_t)5*32*64; A.by = b_y1 + 5*32;
          A.wl = w_last;
          A.pred_out = predbuf + (size_t)step*NB*HW;
          A.final_out = (step >= 8) ? ((float*)d_out + (size_t)(step-8)*HW) : nullptr;
        }
        cell_kernel<<<dim3(64, NB), 512, 0, stream>>>(A);
      }
  }
}